// Round 9
// baseline (387.792 us; speedup 1.0000x reference)
//
#include <hip/hip_runtime.h>

#define T_ 32
#define B_ 32
#define S_ 64
#define C_ 1024
#define H_ 1024
#define NWG 64
#define HSLOT 32768  // ushorts per h ring slot (32 x 1024)

typedef __attribute__((ext_vector_type(8))) short bf16x8;
typedef __attribute__((ext_vector_type(4))) float f32x4;

// d_out layout (float offsets): outputs[32*32*1024], h[32*1024], c[32*1024], attn[32*32*64]
#define OUT_H   1048576
#define OUT_CC  1081344
#define OUT_AT  1114112

__device__ __forceinline__ ushort f2b(float f) {
  unsigned u = __float_as_uint(f);
  unsigned r = (u + 0x7FFFu + ((u >> 16) & 1u)) >> 16;
  return (ushort)r;
}
__device__ __forceinline__ float b2f(ushort h) {
  return __uint_as_float(((unsigned)h) << 16);
}

// ---------------- init: cvt inp+Wih to bf16, v = W2@W1_x, bias, zero h slot0, zero flags ----------------
__global__ __launch_bounds__(256) void k_init(const float* __restrict__ inp, ushort* __restrict__ inpb,
                                              const float* __restrict__ Wih, ushort* __restrict__ Wihb,
                                              const float* __restrict__ W1, const float* __restrict__ W2,
                                              const float* __restrict__ bih, const float* __restrict__ bhh,
                                              float* __restrict__ v, float* __restrict__ bias,
                                              ushort* __restrict__ hring, unsigned* __restrict__ flags) {
  int blk = blockIdx.x, tid = threadIdx.x;
  if (blk < 2560) {
    const float* src; ushort* dst; int base;
    if (blk < 512) { src = inp; dst = inpb; base = blk; }
    else { src = Wih; dst = Wihb; base = blk - 512; }
    size_t i = ((size_t)base * 256 + tid) * 8;
    float4 v0 = *reinterpret_cast<const float4*>(src + i);
    float4 v1 = *reinterpret_cast<const float4*>(src + i + 4);
    uint4 o;
    o.x = (unsigned)f2b(v0.x) | ((unsigned)f2b(v0.y) << 16);
    o.y = (unsigned)f2b(v0.z) | ((unsigned)f2b(v0.w) << 16);
    o.z = (unsigned)f2b(v1.x) | ((unsigned)f2b(v1.y) << 16);
    o.w = (unsigned)f2b(v1.z) | ((unsigned)f2b(v1.w) << 16);
    *reinterpret_cast<uint4*>(dst + i) = o;
  } else if (blk < 2564) {
    int c = (blk - 2560) * 256 + tid;
    float acc = 0.f;
#pragma unroll 8
    for (int a = 0; a < 128; ++a) acc += W1[a * 2048 + 1024 + c] * W2[a];
    v[c] = acc;
  } else if (blk < 2580) {
    int j = (blk - 2564) * 256 + tid;
    bias[j] = bih[j] + bhh[j];
  } else if (blk < 2584) {
    unsigned* hz = reinterpret_cast<unsigned*>(hring);
    int base = (blk - 2580) * 4096;
    for (int i = 0; i < 16; ++i) hz[base + i * 256 + tid] = 0u;
  } else {
    for (int i = 0; i < 4; ++i) flags[i * 256 + tid] = 0u;
  }
}

// ---------------- attention (time-invariant): weights + weighted sum into ws; attn broadcast ----------------
__global__ __launch_bounds__(256) void k_attn(const float* __restrict__ ctx, const float* __restrict__ v,
                                              float* __restrict__ wgt, float* __restrict__ out) {
  int b = blockIdx.x, tid = threadIdx.x;
  int lane = tid & 63, w = tid >> 6;
  __shared__ float v_s[1024];
  __shared__ float sc_s[64];
  __shared__ float att_s[64];
  for (int i = 0; i < 4; ++i) v_s[tid + i * 256] = v[tid + i * 256];
  __syncthreads();
  for (int si = 0; si < 16; ++si) {
    int s = w * 16 + si;
    const float* xr = ctx + (size_t)(s * B_ + b) * C_;
    float acc = 0.f;
#pragma unroll
    for (int i = 0; i < 16; ++i) { int c = lane + i * 64; acc += xr[c] * v_s[c]; }
    for (int off = 32; off; off >>= 1) acc += __shfl_down(acc, off);
    if (lane == 0) sc_s[s] = acc;
  }
  __syncthreads();
  if (tid < 64) {
    float val = sc_s[tid];
    float mx = val;
    for (int off = 32; off; off >>= 1) mx = fmaxf(mx, __shfl_xor(mx, off));
    float e = expf(val - mx);
    float sm = e;
    for (int off = 32; off; off >>= 1) sm += __shfl_xor(sm, off);
    att_s[tid] = e / sm;
  }
  __syncthreads();
  const float4* ctx4 = reinterpret_cast<const float4*>(ctx);
  float4 a4 = {0.f, 0.f, 0.f, 0.f};
  for (int s = 0; s < 64; ++s) {
    float a = att_s[s];
    float4 x = ctx4[(size_t)(s * B_ + b) * 256 + tid];
    a4.x += a * x.x; a4.y += a * x.y; a4.z += a * x.z; a4.w += a * x.w;
  }
  reinterpret_cast<float4*>(wgt + b * 1024)[tid] = a4;
  if (tid < 64) {
    float av = att_s[tid];
#pragma unroll 4
    for (int t = 0; t < T_; ++t) out[OUT_AT + (t * B_ + b) * 64 + tid] = av;
  }
}

// ---------------- x_proj MFMA: xpT[j][m] = sum_k inp[m][k]*W_ih[j][k] + bias[j] ----------------
__global__ __launch_bounds__(256) void k_xproj(const ushort* __restrict__ inpb, const ushort* __restrict__ Wihb,
                                               const float* __restrict__ bias, ushort* __restrict__ xpT) {
  __shared__ int4 A_s[512];  // fragment-contiguous: [kgrp(4)][row(128)] x 16B
  __shared__ int4 B_s[512];
  int tid = threadIdx.x;
  int m0 = (blockIdx.x >> 5) << 7;
  int j0 = (blockIdx.x & 31) << 7;
  int lane = tid & 63, w = tid >> 6;
  int wm = (w >> 1) * 64, wn = (w & 1) * 64;
  int g = lane >> 4, r = lane & 15;
  f32x4 acc[4][4];
#pragma unroll
  for (int mi = 0; mi < 4; ++mi)
#pragma unroll
    for (int ni = 0; ni < 4; ++ni) acc[mi][ni] = (f32x4)(0.f);

  int f0 = tid, r0s = f0 >> 2, g0s = f0 & 3;
  int f1 = tid + 256, r1s = f1 >> 2, g1s = f1 & 3;
  for (int k0 = 0; k0 < 1024; k0 += 32) {
    __syncthreads();
    A_s[g0s * 128 + r0s] = *reinterpret_cast<const int4*>(inpb + (size_t)(m0 + r0s) * 1024 + k0 + g0s * 8);
    B_s[g0s * 128 + r0s] = *reinterpret_cast<const int4*>(Wihb + (size_t)(j0 + r0s) * 1024 + k0 + g0s * 8);
    A_s[g1s * 128 + r1s] = *reinterpret_cast<const int4*>(inpb + (size_t)(m0 + r1s) * 1024 + k0 + g1s * 8);
    B_s[g1s * 128 + r1s] = *reinterpret_cast<const int4*>(Wihb + (size_t)(j0 + r1s) * 1024 + k0 + g1s * 8);
    __syncthreads();
    bf16x8 af[4], bf_[4];
#pragma unroll
    for (int mi = 0; mi < 4; ++mi) af[mi] = *reinterpret_cast<const bf16x8*>(&A_s[g * 128 + wm + mi * 16 + r]);
#pragma unroll
    for (int ni = 0; ni < 4; ++ni) bf_[ni] = *reinterpret_cast<const bf16x8*>(&B_s[g * 128 + wn + ni * 16 + r]);
#pragma unroll
    for (int mi = 0; mi < 4; ++mi)
#pragma unroll
      for (int ni = 0; ni < 4; ++ni)
        acc[mi][ni] = __builtin_amdgcn_mfma_f32_16x16x32_bf16(af[mi], bf_[ni], acc[mi][ni], 0, 0, 0);
  }
  int q = lane >> 4;
#pragma unroll
  for (int ni = 0; ni < 4; ++ni) {
    int j = j0 + wn + ni * 16 + r;
    float bj = bias[j];
#pragma unroll
    for (int mi = 0; mi < 4; ++mi) {
      int mb = m0 + wm + mi * 16 + q * 4;
      uint2 pk;
      pk.x = (unsigned)f2b(acc[mi][ni][0] + bj) | ((unsigned)f2b(acc[mi][ni][1] + bj) << 16);
      pk.y = (unsigned)f2b(acc[mi][ni][2] + bj) | ((unsigned)f2b(acc[mi][ni][3] + bj) << 16);
      *reinterpret_cast<uint2*>(xpT + (size_t)j * 1024 + mb) = pk;
    }
  }
}

// ---------------- persistent recurrence: all 32 LSTM steps, one dispatch ----------------
// 64 WGs x 1024 threads. WG owns hidx [16*wg,16*wg+16) x 4 gates. Wave w: q=w&3, ks=w>>2.
// W_hh fragments converted f32->bf16 in-register at start. Per step: wave polls ONLY its 16
// producers' flags (one 64-lane bypass load), loads its B-fragments straight from the h ring
// (cached; slot written once per launch so cached lines can't be stale), 16 MFMAs, LDS K-
// reduction, epilogue, publish via agent-scope stores + monotonic flag. Outputs broadcast
// (2 KB/WG/step) rides the idle windows. No cache fences anywhere.
__global__ __launch_bounds__(1024, 4) void k_rec(const float* __restrict__ Whh, const ushort* __restrict__ xpT,
                                                 ushort* __restrict__ hring, const float* __restrict__ wgt,
                                                 float* __restrict__ out, unsigned* __restrict__ flags) {
  int tid = threadIdx.x, lane = tid & 63, w = tid >> 6;
  int wg = blockIdx.x;
  int q = w & 3, ks = w >> 2;
  int g = lane >> 4, r = lane & 15;
  int hidx0 = wg * 16 + q * 4;
  int kbase = ks * 256;
  int j = (r >> 2) * 1024 + hidx0 + (r & 3);
  // W_hh fragments: f32 load + in-register bf16 pack (no separate cvt pass / buffer)
  bf16x8 a[8];
  {
    const float* ap = Whh + (size_t)j * 1024 + kbase + g * 8;
#pragma unroll
    for (int kk = 0; kk < 8; ++kk) {
      float4 f0 = *reinterpret_cast<const float4*>(ap + kk * 32);
      float4 f1 = *reinterpret_cast<const float4*>(ap + kk * 32 + 4);
      bf16x8 t8;
      t8[0] = (short)f2b(f0.x); t8[1] = (short)f2b(f0.y);
      t8[2] = (short)f2b(f0.z); t8[3] = (short)f2b(f0.w);
      t8[4] = (short)f2b(f1.x); t8[5] = (short)f2b(f1.y);
      t8[6] = (short)f2b(f1.z); t8[7] = (short)f2b(f1.w);
      a[kk] = t8;
    }
  }
  __shared__ float red[4][4][16][32];   // 32 KB K-slice partials
  __shared__ __align__(16) ushort hs[32][16];
  float c_reg = 0.f;
  int eb = tid & 31, hl = (tid >> 5) & 3, qq = tid >> 7;  // epilogue cell (tid<512)
  int ehidx = wg * 16 + qq * 4 + hl;
  int pidx = (ks * 16 + (lane & 15)) * 16;  // this wave's producer-flag slot

  // prefetch xpT slice for t=0 (cached; xpT stays L2-resident — no invalidations anywhere)
  float xf_i = 0.f, xf_f = 0.f, xf_g = 0.f, xf_o = 0.f;
  if (tid < 512) {
    xf_i = b2f(xpT[(size_t)(ehidx) * 1024 + eb]);
    xf_f = b2f(xpT[(size_t)(1024 + ehidx) * 1024 + eb]);
    xf_g = b2f(xpT[(size_t)(2048 + ehidx) * 1024 + eb]);
    xf_o = b2f(xpT[(size_t)(3072 + ehidx) * 1024 + eb]);
  }

#pragma unroll 1
  for (int t = 0; t < T_; ++t) {
    // per-wave poll: only the 16 WGs producing h[kbase..kbase+256) gate this wave
    if (t > 0) {
      for (;;) {
        unsigned vfl = __hip_atomic_load(&flags[pidx], __ATOMIC_RELAXED, __HIP_MEMORY_SCOPE_AGENT);
        if (__all((int)(vfl >= (unsigned)t))) break;
        __builtin_amdgcn_s_sleep(1);
      }
    }
    // B-fragments straight from the ring slot (plain cached loads)
    const ushort* bp = hring + (size_t)t * HSLOT + (size_t)r * 1024 + kbase + g * 8;
    f32x4 acc0 = (f32x4)(0.f), acc1 = (f32x4)(0.f);
#pragma unroll
    for (int kk = 0; kk < 8; ++kk) {
      bf16x8 b0 = *reinterpret_cast<const bf16x8*>(bp + kk * 32);
      bf16x8 b1 = *reinterpret_cast<const bf16x8*>(bp + 16 * 1024 + kk * 32);
      acc0 = __builtin_amdgcn_mfma_f32_16x16x32_bf16(a[kk], b0, acc0, 0, 0, 0);
      acc1 = __builtin_amdgcn_mfma_f32_16x16x32_bf16(a[kk], b1, acc1, 0, 0, 0);
    }
#pragma unroll
    for (int e = 0; e < 4; ++e) {
      red[q][ks][g * 4 + e][r] = acc0[e];
      red[q][ks][g * 4 + e][r + 16] = acc1[e];
    }
    __syncthreads();
    if (tid < 512) {
      float ig = red[qq][0][0 + hl][eb]  + red[qq][1][0 + hl][eb]  + red[qq][2][0 + hl][eb]  + red[qq][3][0 + hl][eb]  + xf_i;
      float fg = red[qq][0][4 + hl][eb]  + red[qq][1][4 + hl][eb]  + red[qq][2][4 + hl][eb]  + red[qq][3][4 + hl][eb]  + xf_f;
      float gg = red[qq][0][8 + hl][eb]  + red[qq][1][8 + hl][eb]  + red[qq][2][8 + hl][eb]  + red[qq][3][8 + hl][eb]  + xf_g;
      float og = red[qq][0][12 + hl][eb] + red[qq][1][12 + hl][eb] + red[qq][2][12 + hl][eb] + red[qq][3][12 + hl][eb] + xf_o;
      float si = 1.f / (1.f + __expf(-ig));
      float sf = 1.f / (1.f + __expf(-fg));
      float so = 1.f / (1.f + __expf(-og));
      float c_new = sf * c_reg + si * tanhf(gg);
      float h_new = so * tanhf(c_new);
      c_reg = c_new;
      hs[eb][qq * 4 + hl] = f2b(h_new);
      if (t == T_ - 1) {
        out[OUT_H + eb * 1024 + ehidx] = h_new;
        out[OUT_CC + eb * 1024 + ehidx] = c_new;
      }
    }
    __syncthreads();  // hs ready (also fences red across iterations)
    if (t != T_ - 1) {
      if (w == 0) {
        // publish h slice via agent-scope (coherence-point) dword stores + monotonic flag
        ushort* hout = hring + (size_t)(t + 1) * HSLOT;
        int b = lane >> 1, half = lane & 1;
        uint4 vv = *reinterpret_cast<const uint4*>(&hs[b][half * 8]);
        unsigned* hp = reinterpret_cast<unsigned*>(hout) + b * 512 + wg * 8 + half * 4;
        __hip_atomic_store(hp + 0, vv.x, __ATOMIC_RELAXED, __HIP_MEMORY_SCOPE_AGENT);
        __hip_atomic_store(hp + 1, vv.y, __ATOMIC_RELAXED, __HIP_MEMORY_SCOPE_AGENT);
        __hip_atomic_store(hp + 2, vv.z, __ATOMIC_RELAXED, __HIP_MEMORY_SCOPE_AGENT);
        __hip_atomic_store(hp + 3, vv.w, __ATOMIC_RELAXED, __HIP_MEMORY_SCOPE_AGENT);
        asm volatile("s_waitcnt vmcnt(0)" ::: "memory");
        if (lane == 0)
          __hip_atomic_store(&flags[wg * 16], (unsigned)(t + 1), __ATOMIC_RELAXED, __HIP_MEMORY_SCOPE_AGENT);
      }
      // prefetch next xpT slice (off the critical path, overlaps the poll)
      float nx_i = 0.f, nx_f = 0.f, nx_g = 0.f, nx_o = 0.f;
      if (tid < 512) {
        int mnext = (t + 1) * 32 + eb;
        nx_i = b2f(xpT[(size_t)(ehidx) * 1024 + mnext]);
        nx_f = b2f(xpT[(size_t)(1024 + ehidx) * 1024 + mnext]);
        nx_g = b2f(xpT[(size_t)(2048 + ehidx) * 1024 + mnext]);
        nx_o = b2f(xpT[(size_t)(3072 + ehidx) * 1024 + mnext]);
      }
      xf_i = nx_i; xf_f = nx_f; xf_g = nx_g; xf_o = nx_o;
    }
    // outputs broadcast for step t (fire-and-forget; 2 KB per WG)
    if (tid < 128) {
      int off = ((wg & 1) << 9) + (tid << 2);
      float4 vv = *reinterpret_cast<const float4*>(wgt + ((wg >> 1) << 10) + off);
      *reinterpret_cast<float4*>(out + ((size_t)(t * 32 + (wg >> 1)) << 10) + off) = vv;
    }
  }
}

extern "C" void kernel_launch(void* const* d_in, const int* in_sizes, int n_in,
                              void* d_out, int out_size, void* d_ws, size_t ws_size,
                              hipStream_t stream) {
  const float* inp = (const float*)d_in[0];
  const float* ctx = (const float*)d_in[1];
  const float* Wih = (const float*)d_in[2];
  const float* Whh = (const float*)d_in[3];
  const float* bih = (const float*)d_in[4];
  const float* bhh = (const float*)d_in[5];
  const float* W1  = (const float*)d_in[6];
  const float* W2  = (const float*)d_in[8];
  float* out = (float*)d_out;
  char* wsb = (char*)d_ws;

  float* v     = (float*)(wsb + 0);          // 4 KB
  float* bias  = (float*)(wsb + 4096);       // 16 KB
  float* wgt   = (float*)(wsb + 20480);      // 128 KB
  ushort* hring = (ushort*)(wsb + 151552);   // 33 slots x 64 KB = 2112 KB
  ushort* inpb = (ushort*)(wsb + 2314240);   // 2 MB
  ushort* Wihb = (ushort*)(wsb + 4411392);   // 8 MB
  ushort* xpT  = (ushort*)(wsb + 12800000);  // 8 MB
  unsigned* flags = (unsigned*)(wsb + 21188608); // 4 KB (64 flags, 64B apart)

  hipLaunchKernelGGL(k_init, dim3(2585), dim3(256), 0, stream,
                     inp, inpb, Wih, Wihb, W1, W2, bih, bhh, v, bias, hring, flags);
  hipLaunchKernelGGL(k_attn, dim3(32), dim3(256), 0, stream, ctx, v, wgt, out);
  hipLaunchKernelGGL(k_xproj, dim3(256), dim3(256), 0, stream, inpb, Wihb, bias, xpT);

  const float* Whh_c = Whh;
  const ushort* xpT_c = xpT;
  const float* wgt_c = wgt;
  void* kargs[6];
  kargs[0] = (void*)&Whh_c;
  kargs[1] = (void*)&xpT_c;
  kargs[2] = (void*)&hring;
  kargs[3] = (void*)&wgt_c;
  kargs[4] = (void*)&out;
  kargs[5] = (void*)&flags;
  hipLaunchCooperativeKernel((const void*)k_rec, dim3(NWG), dim3(1024), kargs, 0, stream);
}

// Round 11
// 217.718 us; speedup vs baseline: 1.7812x; 1.7812x over previous
//
#include <hip/hip_runtime.h>

#define T_ 32
#define B_ 32
#define S_ 64
#define C_ 1024
#define H_ 1024
#define NWG 64
#define HSLOT 32768  // ushorts per h ring slot / per x_t slab (32 x 1024)

typedef __attribute__((ext_vector_type(8))) short bf16x8;
typedef __attribute__((ext_vector_type(4))) float f32x4;

// d_out layout (float offsets): outputs[32*32*1024], h[32*1024], c[32*1024], attn[32*32*64]
#define OUT_H   1048576
#define OUT_CC  1081344
#define OUT_AT  1114112

__device__ __forceinline__ ushort f2b(float f) {
  unsigned u = __float_as_uint(f);
  unsigned r = (u + 0x7FFFu + ((u >> 16) & 1u)) >> 16;
  return (ushort)r;
}
__device__ __forceinline__ float b2f(ushort h) {
  return __uint_as_float(((unsigned)h) << 16);
}

// ---------------- init: cvt inp/Wih/Whh to bf16, v = W2@W1_x, bias, zero h slot0, zero flags ----------------
__global__ __launch_bounds__(256) void k_init(const float* __restrict__ inp, ushort* __restrict__ inpb,
                                              const float* __restrict__ Wih, ushort* __restrict__ Wihb,
                                              const float* __restrict__ Whh, ushort* __restrict__ Whhb,
                                              const float* __restrict__ W1, const float* __restrict__ W2,
                                              const float* __restrict__ bih, const float* __restrict__ bhh,
                                              float* __restrict__ v, float* __restrict__ bias,
                                              ushort* __restrict__ hring, unsigned* __restrict__ flags) {
  int blk = blockIdx.x, tid = threadIdx.x;
  if (blk < 4608) {
    const float* src; ushort* dst; int base;
    if (blk < 512) { src = inp; dst = inpb; base = blk; }
    else if (blk < 2560) { src = Wih; dst = Wihb; base = blk - 512; }
    else { src = Whh; dst = Whhb; base = blk - 2560; }
    size_t i = ((size_t)base * 256 + tid) * 8;
    float4 v0 = *reinterpret_cast<const float4*>(src + i);
    float4 v1 = *reinterpret_cast<const float4*>(src + i + 4);
    uint4 o;
    o.x = (unsigned)f2b(v0.x) | ((unsigned)f2b(v0.y) << 16);
    o.y = (unsigned)f2b(v0.z) | ((unsigned)f2b(v0.w) << 16);
    o.z = (unsigned)f2b(v1.x) | ((unsigned)f2b(v1.y) << 16);
    o.w = (unsigned)f2b(v1.z) | ((unsigned)f2b(v1.w) << 16);
    *reinterpret_cast<uint4*>(dst + i) = o;
  } else if (blk < 4612) {
    int c = (blk - 4608) * 256 + tid;
    float acc = 0.f;
#pragma unroll 8
    for (int a = 0; a < 128; ++a) acc += W1[a * 2048 + 1024 + c] * W2[a];
    v[c] = acc;
  } else if (blk < 4628) {
    int jj = (blk - 4612) * 256 + tid;
    bias[jj] = bih[jj] + bhh[jj];
  } else if (blk < 4632) {
    unsigned* hz = reinterpret_cast<unsigned*>(hring);
    int base = (blk - 4628) * 4096;
    for (int i = 0; i < 16; ++i) hz[base + i * 256 + tid] = 0u;
  } else {
    for (int i = 0; i < 4; ++i) flags[i * 256 + tid] = 0u;
  }
}

// ---------------- attention (time-invariant): weighted sum into ws; attn broadcast ----------------
__global__ __launch_bounds__(256) void k_attn(const float* __restrict__ ctx, const float* __restrict__ v,
                                              float* __restrict__ wgt, float* __restrict__ out) {
  int b = blockIdx.x, tid = threadIdx.x;
  int lane = tid & 63, w = tid >> 6;
  __shared__ float v_s[1024];
  __shared__ float sc_s[64];
  __shared__ float att_s[64];
  for (int i = 0; i < 4; ++i) v_s[tid + i * 256] = v[tid + i * 256];
  __syncthreads();
  for (int si = 0; si < 16; ++si) {
    int s = w * 16 + si;
    const float* xr = ctx + (size_t)(s * B_ + b) * C_;
    float acc = 0.f;
#pragma unroll
    for (int i = 0; i < 16; ++i) { int c = lane + i * 64; acc += xr[c] * v_s[c]; }
    for (int off = 32; off; off >>= 1) acc += __shfl_down(acc, off);
    if (lane == 0) sc_s[s] = acc;
  }
  __syncthreads();
  if (tid < 64) {
    float val = sc_s[tid];
    float mx = val;
    for (int off = 32; off; off >>= 1) mx = fmaxf(mx, __shfl_xor(mx, off));
    float e = expf(val - mx);
    float sm = e;
    for (int off = 32; off; off >>= 1) sm += __shfl_xor(sm, off);
    att_s[tid] = e / sm;
  }
  __syncthreads();
  const float4* ctx4 = reinterpret_cast<const float4*>(ctx);
  float4 a4 = {0.f, 0.f, 0.f, 0.f};
  for (int s = 0; s < 64; ++s) {
    float a = att_s[s];
    float4 x = ctx4[(size_t)(s * B_ + b) * 256 + tid];
    a4.x += a * x.x; a4.y += a * x.y; a4.z += a * x.z; a4.w += a * x.w;
  }
  reinterpret_cast<float4*>(wgt + b * 1024)[tid] = a4;
  if (tid < 64) {
    float av = att_s[tid];
#pragma unroll 4
    for (int t = 0; t < T_; ++t) out[OUT_AT + (t * B_ + b) * 64 + tid] = av;
  }
}

// ---------------- persistent recurrence + fused x-projection: all 32 steps, one dispatch ----------------
// 64 WGs x 1024 threads. WG owns hidx [16*wg,16*wg+16) x 4 gates. Wave w: q=w&3, ks=w>>2.
// W_hh AND W_ih fragments register-resident (bf16). Per step: stage x_t -> LDS and run its
// 16 MFMAs BEFORE the poll (fills the publish->poll idle window), then w0 polls all 64 flags
// (one 64-lane bypass load), restage h slot t into the same LDS, 16 h-MFMAs into the same
// accumulator, LDS K-reduction, epilogue (+bias in f32 regs), publish h via agent-scope
// stores + monotonic flag. Outputs broadcast rides on waves 8-9. No cache fences anywhere.
__global__ __launch_bounds__(1024, 4) void k_rec(const ushort* __restrict__ Whhb, const ushort* __restrict__ Wihb,
                                                 const ushort* __restrict__ inpb, ushort* __restrict__ hring,
                                                 const float* __restrict__ wgt, const float* __restrict__ bias,
                                                 float* __restrict__ out, unsigned* __restrict__ flags) {
  int tid = threadIdx.x, lane = tid & 63, w = tid >> 6;
  int wg = blockIdx.x;
  int q = w & 3, ks = w >> 2;
  int g = lane >> 4, r = lane & 15;
  int hidx0 = wg * 16 + q * 4;
  int kbase = ks * 256;
  int j = (r >> 2) * 1024 + hidx0 + (r & 3);
  bf16x8 ah[8], ax[8];
  {
    const ushort* ap = Whhb + (size_t)j * 1024 + kbase + g * 8;
    const ushort* axp = Wihb + (size_t)j * 1024 + kbase + g * 8;
#pragma unroll
    for (int kk = 0; kk < 8; ++kk) {
      ah[kk] = *reinterpret_cast<const bf16x8*>(ap + kk * 32);
      ax[kk] = *reinterpret_cast<const bf16x8*>(axp + kk * 32);
    }
  }
  __shared__ uint4 hl4[4096];           // 64 KB staging (x_t, then h): idx = row*128 + (c16 ^ (row&7))
  __shared__ float red[4][4][16][32];   // 32 KB K-slice partials
  __shared__ __align__(16) ushort hs[32][16];
  float c_reg = 0.f;
  int eb = tid & 31, hl = (tid >> 5) & 3, qq = tid >> 7;  // epilogue cell (tid<512)
  int ehidx = wg * 16 + qq * 4 + hl;
  float bs_i = 0.f, bs_f = 0.f, bs_g = 0.f, bs_o = 0.f;
  if (tid < 512) {
    bs_i = bias[ehidx];
    bs_f = bias[1024 + ehidx];
    bs_g = bias[2048 + ehidx];
    bs_o = bias[3072 + ehidx];
  }
  int cb = ks * 32 + g;

#pragma unroll 1
  for (int t = 0; t < T_; ++t) {
    // ---- phase X: stage x_t (no dependency) and accumulate W_ih @ x_t ----
    {
      const uint4* s4 = reinterpret_cast<const uint4*>(inpb + (size_t)t * HSLOT);
      uint4 v0 = s4[tid], v1 = s4[tid + 1024], v2 = s4[tid + 2048], v3 = s4[tid + 3072];
      int c0 = tid, c1 = tid + 1024, c2 = tid + 2048, c3 = tid + 3072;
      hl4[(c0 >> 7) * 128 + ((c0 & 127) ^ ((c0 >> 7) & 7))] = v0;
      hl4[(c1 >> 7) * 128 + ((c1 & 127) ^ ((c1 >> 7) & 7))] = v1;
      hl4[(c2 >> 7) * 128 + ((c2 & 127) ^ ((c2 >> 7) & 7))] = v2;
      hl4[(c3 >> 7) * 128 + ((c3 & 127) ^ ((c3 >> 7) & 7))] = v3;
    }
    __syncthreads();
    f32x4 acc0 = (f32x4)(0.f), acc1 = (f32x4)(0.f);
#pragma unroll
    for (int kk = 0; kk < 8; ++kk) {
      int c16 = cb + kk * 4;
      bf16x8 b0 = *reinterpret_cast<const bf16x8*>(&hl4[r * 128 + (c16 ^ (r & 7))]);
      bf16x8 b1 = *reinterpret_cast<const bf16x8*>(&hl4[(r + 16) * 128 + (c16 ^ (r & 7))]);
      acc0 = __builtin_amdgcn_mfma_f32_16x16x32_bf16(ax[kk], b0, acc0, 0, 0, 0);
      acc1 = __builtin_amdgcn_mfma_f32_16x16x32_bf16(ax[kk], b1, acc1, 0, 0, 0);
    }
    // ---- poll: single wave, all 64 producer flags, one 64-lane bypass load ----
    if (t > 0 && w == 0) {
      for (;;) {
        unsigned vfl = __hip_atomic_load(&flags[lane * 16], __ATOMIC_RELAXED, __HIP_MEMORY_SCOPE_AGENT);
        if (__all((int)(vfl >= (unsigned)t))) break;
        __builtin_amdgcn_s_sleep(1);
      }
    }
    __syncthreads();  // gates h restage; all waves done reading x from hl4
    // ---- phase H: stage h slot t, accumulate W_hh @ h ----
    {
      const uint4* s4 = reinterpret_cast<const uint4*>(hring + (size_t)t * HSLOT);
      uint4 v0 = s4[tid], v1 = s4[tid + 1024], v2 = s4[tid + 2048], v3 = s4[tid + 3072];
      int c0 = tid, c1 = tid + 1024, c2 = tid + 2048, c3 = tid + 3072;
      hl4[(c0 >> 7) * 128 + ((c0 & 127) ^ ((c0 >> 7) & 7))] = v0;
      hl4[(c1 >> 7) * 128 + ((c1 & 127) ^ ((c1 >> 7) & 7))] = v1;
      hl4[(c2 >> 7) * 128 + ((c2 & 127) ^ ((c2 >> 7) & 7))] = v2;
      hl4[(c3 >> 7) * 128 + ((c3 & 127) ^ ((c3 >> 7) & 7))] = v3;
    }
    __syncthreads();
#pragma unroll
    for (int kk = 0; kk < 8; ++kk) {
      int c16 = cb + kk * 4;
      bf16x8 b0 = *reinterpret_cast<const bf16x8*>(&hl4[r * 128 + (c16 ^ (r & 7))]);
      bf16x8 b1 = *reinterpret_cast<const bf16x8*>(&hl4[(r + 16) * 128 + (c16 ^ (r & 7))]);
      acc0 = __builtin_amdgcn_mfma_f32_16x16x32_bf16(ah[kk], b0, acc0, 0, 0, 0);
      acc1 = __builtin_amdgcn_mfma_f32_16x16x32_bf16(ah[kk], b1, acc1, 0, 0, 0);
    }
#pragma unroll
    for (int e = 0; e < 4; ++e) {
      red[q][ks][g * 4 + e][r] = acc0[e];
      red[q][ks][g * 4 + e][r + 16] = acc1[e];
    }
    __syncthreads();
    if (tid < 512) {
      float ig = red[qq][0][0 + hl][eb]  + red[qq][1][0 + hl][eb]  + red[qq][2][0 + hl][eb]  + red[qq][3][0 + hl][eb]  + bs_i;
      float fg = red[qq][0][4 + hl][eb]  + red[qq][1][4 + hl][eb]  + red[qq][2][4 + hl][eb]  + red[qq][3][4 + hl][eb]  + bs_f;
      float gg = red[qq][0][8 + hl][eb]  + red[qq][1][8 + hl][eb]  + red[qq][2][8 + hl][eb]  + red[qq][3][8 + hl][eb]  + bs_g;
      float og = red[qq][0][12 + hl][eb] + red[qq][1][12 + hl][eb] + red[qq][2][12 + hl][eb] + red[qq][3][12 + hl][eb] + bs_o;
      float si = 1.f / (1.f + __expf(-ig));
      float sf = 1.f / (1.f + __expf(-fg));
      float so = 1.f / (1.f + __expf(-og));
      float c_new = sf * c_reg + si * tanhf(gg);
      float h_new = so * tanhf(c_new);
      c_reg = c_new;
      hs[eb][qq * 4 + hl] = f2b(h_new);
      if (t == T_ - 1) {
        out[OUT_H + eb * 1024 + ehidx] = h_new;
        out[OUT_CC + eb * 1024 + ehidx] = c_new;
      }
    }
    __syncthreads();  // hs ready
    if (t != T_ - 1 && w == 0) {
      // publish h slice via agent-scope (coherence-point) dword stores + monotonic flag
      ushort* hout = hring + (size_t)(t + 1) * HSLOT;
      int b = lane >> 1, half = lane & 1;
      uint4 vv = *reinterpret_cast<const uint4*>(&hs[b][half * 8]);
      unsigned* hp = reinterpret_cast<unsigned*>(hout) + b * 512 + wg * 8 + half * 4;
      __hip_atomic_store(hp + 0, vv.x, __ATOMIC_RELAXED, __HIP_MEMORY_SCOPE_AGENT);
      __hip_atomic_store(hp + 1, vv.y, __ATOMIC_RELAXED, __HIP_MEMORY_SCOPE_AGENT);
      __hip_atomic_store(hp + 2, vv.z, __ATOMIC_RELAXED, __HIP_MEMORY_SCOPE_AGENT);
      __hip_atomic_store(hp + 3, vv.w, __ATOMIC_RELAXED, __HIP_MEMORY_SCOPE_AGENT);
      asm volatile("s_waitcnt vmcnt(0)" ::: "memory");
      if (lane == 0)
        __hip_atomic_store(&flags[wg * 16], (unsigned)(t + 1), __ATOMIC_RELAXED, __HIP_MEMORY_SCOPE_AGENT);
    }
    // outputs broadcast for step t (waves 8-9: idle during epilogue/publish; no vmcnt coupling with w0)
    if (tid >= 512 && tid < 640) {
      int lcl = tid - 512;
      int off = ((wg & 1) << 9) + (lcl << 2);
      float4 vv = *reinterpret_cast<const float4*>(wgt + ((wg >> 1) << 10) + off);
      *reinterpret_cast<float4*>(out + ((size_t)(t * 32 + (wg >> 1)) << 10) + off) = vv;
    }
  }
}

extern "C" void kernel_launch(void* const* d_in, const int* in_sizes, int n_in,
                              void* d_out, int out_size, void* d_ws, size_t ws_size,
                              hipStream_t stream) {
  const float* inp = (const float*)d_in[0];
  const float* ctx = (const float*)d_in[1];
  const float* Wih = (const float*)d_in[2];
  const float* Whh = (const float*)d_in[3];
  const float* bih = (const float*)d_in[4];
  const float* bhh = (const float*)d_in[5];
  const float* W1  = (const float*)d_in[6];
  const float* W2  = (const float*)d_in[8];
  float* out = (float*)d_out;
  char* wsb = (char*)d_ws;

  float* v     = (float*)(wsb + 0);          // 4 KB
  float* bias  = (float*)(wsb + 4096);       // 16 KB
  float* wgt   = (float*)(wsb + 20480);      // 128 KB
  ushort* hring = (ushort*)(wsb + 151552);   // 33 slots x 64 KB = 2112 KB
  ushort* inpb = (ushort*)(wsb + 2314240);   // 2 MB
  ushort* Wihb = (ushort*)(wsb + 4411392);   // 8 MB
  ushort* Whhb = (ushort*)(wsb + 12800000);  // 8 MB
  unsigned* flags = (unsigned*)(wsb + 21188608); // 4 KB (64 flags, 64B apart)

  hipLaunchKernelGGL(k_init, dim3(4633), dim3(256), 0, stream,
                     inp, inpb, Wih, Wihb, Whh, Whhb, W1, W2, bih, bhh, v, bias, hring, flags);
  hipLaunchKernelGGL(k_attn, dim3(32), dim3(256), 0, stream, ctx, v, wgt, out);

  const ushort* Whhb_c = Whhb;
  const ushort* Wihb_c = Wihb;
  const ushort* inpb_c = inpb;
  const float* wgt_c = wgt;
  const float* bias_c = bias;
  void* kargs[8];
  kargs[0] = (void*)&Whhb_c;
  kargs[1] = (void*)&Wihb_c;
  kargs[2] = (void*)&inpb_c;
  kargs[3] = (void*)&hring;
  kargs[4] = (void*)&wgt_c;
  kargs[5] = (void*)&bias_c;
  kargs[6] = (void*)&out;
  kargs[7] = (void*)&flags;
  hipLaunchCooperativeKernel((const void*)k_rec, dim3(NWG), dim3(1024), kargs, 0, stream);
}